// Round 6
// baseline (511.745 us; speedup 1.0000x reference)
//
#include <hip/hip_runtime.h>

typedef unsigned short ushort_t;
typedef __bf16 bf16x8 __attribute__((ext_vector_type(8)));
typedef float f32x4 __attribute__((ext_vector_type(4)));

#define BB 4
#define TT 2048
#define DIMD 1024
#define NH 16
#define DK 64
#define MROWS (BB * TT)   /* 8192 */
#define NQKV (3 * DIMD)   /* 3072 */

__device__ __forceinline__ ushort_t f2b(float f) {
  __bf16 h = (__bf16)f;
  union { __bf16 h; ushort_t u; } c; c.h = h; return c.u;
}

// C[m,n] = sum_k A[m,k] * W[n,k] + bias[n]
// A: [M,K] f32 (A_F32) or bf16; W: [N,K] f32 (cast to bf16 in staging);
// bias: [N] f32; C: [M,N] f32 (OUT_F32) or bf16.
template <bool A_F32, bool OUT_F32>
__global__ __launch_bounds__(256) void gemm_bt_bias(
    const void* __restrict__ Ap, const float* __restrict__ Wf,
    const float* __restrict__ bias, void* __restrict__ Cp,
    int M, int N, int K)
{
  __shared__ __align__(16) ushort_t As[128][32];
  __shared__ __align__(16) ushort_t Bs[128][32];

  const int tid = threadIdx.x;
  const int wave = tid >> 6, lane = tid & 63;
  const int tiles_n = N >> 7;
  const int bm = blockIdx.x / tiles_n, bn = blockIdx.x % tiles_n;
  const int row0 = bm << 7, col0 = bn << 7;
  const int wm = (wave >> 1) << 6;
  const int wn = (wave & 1) << 6;
  const int fr = lane & 15;
  const int fk = (lane >> 4) << 3;
  const int g4 = (lane >> 4) << 2;
  const int srow = tid >> 1;
  const int sc0  = (tid & 1) << 4;

  f32x4 acc[4][4] = {};

  for (int k0 = 0; k0 < K; k0 += 32) {
    ushort_t abuf[16], wbuf[16];
    if constexpr (A_F32) {
      const float* s = (const float*)Ap + (size_t)(row0 + srow) * K + (k0 + sc0);
#pragma unroll
      for (int q = 0; q < 4; ++q) {
        float4 f = *(const float4*)(s + q * 4);
        abuf[q * 4 + 0] = f2b(f.x); abuf[q * 4 + 1] = f2b(f.y);
        abuf[q * 4 + 2] = f2b(f.z); abuf[q * 4 + 3] = f2b(f.w);
      }
    } else {
      const ushort_t* s = (const ushort_t*)Ap + (size_t)(row0 + srow) * K + (k0 + sc0);
      *(uint4*)&abuf[0] = *(const uint4*)s;
      *(uint4*)&abuf[8] = *(const uint4*)(s + 8);
    }
    {
      const float* s = Wf + (size_t)(col0 + srow) * K + (k0 + sc0);
#pragma unroll
      for (int q = 0; q < 4; ++q) {
        float4 f = *(const float4*)(s + q * 4);
        wbuf[q * 4 + 0] = f2b(f.x); wbuf[q * 4 + 1] = f2b(f.y);
        wbuf[q * 4 + 2] = f2b(f.z); wbuf[q * 4 + 3] = f2b(f.w);
      }
    }
    __syncthreads();
    *(uint4*)&As[srow][sc0]     = *(const uint4*)&abuf[0];
    *(uint4*)&As[srow][sc0 + 8] = *(const uint4*)&abuf[8];
    *(uint4*)&Bs[srow][sc0]     = *(const uint4*)&wbuf[0];
    *(uint4*)&Bs[srow][sc0 + 8] = *(const uint4*)&wbuf[8];
    __syncthreads();

    bf16x8 af[4], bw[4];
#pragma unroll
    for (int i = 0; i < 4; ++i) {
      af[i] = *(const bf16x8*)&As[wm + (i << 4) + fr][fk];
      bw[i] = *(const bf16x8*)&Bs[wn + (i << 4) + fr][fk];
    }
#pragma unroll
    for (int mi = 0; mi < 4; ++mi)
#pragma unroll
      for (int ni = 0; ni < 4; ++ni)
        acc[mi][ni] = __builtin_amdgcn_mfma_f32_16x16x32_bf16(af[mi], bw[ni], acc[mi][ni], 0, 0, 0);
  }

#pragma unroll
  for (int ni = 0; ni < 4; ++ni) {
    const int col = col0 + wn + (ni << 4) + fr;
    const float bv = bias[col];
#pragma unroll
    for (int mi = 0; mi < 4; ++mi)
#pragma unroll
      for (int r = 0; r < 4; ++r) {
        const size_t row = (size_t)(row0 + wm + (mi << 4) + g4 + r);
        if constexpr (OUT_F32)
          ((float*)Cp)[row * (size_t)N + col] = acc[mi][ni][r] + bv;
        else
          ((ushort_t*)Cp)[row * (size_t)N + col] = f2b(acc[mi][ni][r] + bv);
      }
  }
}

// async global->LDS, 16B per lane; LDS dest is wave-uniform base + lane*16
__device__ __forceinline__ void gload_lds16(const void* g, void* l) {
  __builtin_amdgcn_global_load_lds(
      (const __attribute__((address_space(1))) void*)g,
      (__attribute__((address_space(3))) void*)l,
      16, 0, 0);
}

// Fused causal flash attention over qkv[M,3072] -> ctx[M,1024] (bf16)
__global__ __launch_bounds__(256) void attn_fused(
    const ushort_t* __restrict__ qkv, ushort_t* __restrict__ ctx)
{
  __shared__ __align__(16) ushort_t Qs[64][64];
  __shared__ __align__(16) ushort_t Ks[64][64];
  __shared__ __align__(16) ushort_t Vt[64][64];       // transposed: Vt[d][kv]
  __shared__ __align__(16) ushort_t Ps[4][16][64];    // per-wave P tile

  const int tid = threadIdx.x, wave = tid >> 6, lane = tid & 63;
  const int fr = lane & 15;
  const int fk = (lane >> 4) << 3;
  const int g4 = (lane >> 4) << 2;

  const int qt = blockIdx.x & 31;            // q tile (T/64 = 32)
  const int h  = (blockIdx.x >> 5) & 15;
  const int b  = blockIdx.x >> 9;

  const size_t qrow0 = (size_t)b * TT + (size_t)qt * 64;
  const ushort_t* Qg = qkv + qrow0 * NQKV + h * DK;

#pragma unroll
  for (int p = 0; p < 2; ++p) {
    const int lds_off = (wave << 10) + (p << 12);
    const int e  = lds_off >> 1;
    const int el = e + lane * 8;
    const int rr = el >> 6, cc = el & 63;
    gload_lds16(Qg + (size_t)rr * NQKV + cc, (ushort_t*)Qs + e);
  }

  float mrow[4] = {-1e30f, -1e30f, -1e30f, -1e30f};
  float lrow[4] = {0.f, 0.f, 0.f, 0.f};
  f32x4 oacc[4] = {};

  for (int kt = 0; kt <= qt; ++kt) {
    __syncthreads();
    const size_t krow0 = (size_t)b * TT + (size_t)kt * 64;
    const ushort_t* Kg = qkv + krow0 * NQKV + DIMD + h * DK;
    const ushort_t* Vg = qkv + krow0 * NQKV + 2 * DIMD + h * DK;

#pragma unroll
    for (int p = 0; p < 2; ++p) {
      const int lds_off = (wave << 10) + (p << 12);
      const int e  = lds_off >> 1;
      const int el = e + lane * 8;
      const int rr = el >> 6, cc = el & 63;
      gload_lds16(Kg + (size_t)rr * NQKV + cc, (ushort_t*)Ks + e);
    }
    {
      const int r  = tid >> 2;
      const int c0 = (tid & 3) << 4;
      const ushort_t* src = Vg + (size_t)r * NQKV + c0;
      ushort_t tmp[16];
      *(uint4*)&tmp[0] = *(const uint4*)&src[0];
      *(uint4*)&tmp[8] = *(const uint4*)&src[8];
#pragma unroll
      for (int j = 0; j < 16; ++j) Vt[c0 + j][r] = tmp[j];
    }
    __syncthreads();

    f32x4 s[4] = {};
#pragma unroll
    for (int ks = 0; ks < 2; ++ks) {
      const bf16x8 aq = *(const bf16x8*)&Qs[(wave << 4) + fr][(ks << 5) + fk];
#pragma unroll
      for (int ni = 0; ni < 4; ++ni) {
        const bf16x8 bk = *(const bf16x8*)&Ks[(ni << 4) + fr][(ks << 5) + fk];
        s[ni] = __builtin_amdgcn_mfma_f32_16x16x32_bf16(aq, bk, s[ni], 0, 0, 0);
      }
    }

    float p[4][4];
#pragma unroll
    for (int r = 0; r < 4; ++r) {
      const int qrow = (qt << 6) + (wave << 4) + g4 + r;
      float rm = -1e30f;
#pragma unroll
      for (int ni = 0; ni < 4; ++ni) {
        float sc = s[ni][r] * 0.125f;
        const int kc = (kt << 6) + (ni << 4) + fr;
        sc = (kc <= qrow) ? sc : -1e30f;
        p[ni][r] = sc;
        rm = fmaxf(rm, sc);
      }
#pragma unroll
      for (int off = 1; off < 16; off <<= 1)
        rm = fmaxf(rm, __shfl_xor(rm, off, 64));
      const float mn = fmaxf(mrow[r], rm);
      const float corr = __expf(mrow[r] - mn);
      mrow[r] = mn;
      float rs = 0.f;
#pragma unroll
      for (int ni = 0; ni < 4; ++ni) {
        const float pe = __expf(p[ni][r] - mn);
        p[ni][r] = pe;
        rs += pe;
      }
#pragma unroll
      for (int off = 1; off < 16; off <<= 1)
        rs += __shfl_xor(rs, off, 64);
      lrow[r] = lrow[r] * corr + rs;
#pragma unroll
      for (int ni = 0; ni < 4; ++ni) oacc[ni][r] *= corr;
    }

#pragma unroll
    for (int r = 0; r < 4; ++r)
#pragma unroll
      for (int ni = 0; ni < 4; ++ni)
        Ps[wave][g4 + r][(ni << 4) + fr] = f2b(p[ni][r]);

    asm volatile("s_waitcnt lgkmcnt(0)" ::: "memory");
    __builtin_amdgcn_sched_barrier(0);

#pragma unroll
    for (int ks = 0; ks < 2; ++ks) {
      const bf16x8 ap = *(const bf16x8*)&Ps[wave][fr][(ks << 5) + fk];
#pragma unroll
      for (int ni = 0; ni < 4; ++ni) {
        const bf16x8 bv = *(const bf16x8*)&Vt[(ni << 4) + fr][(ks << 5) + fk];
        oacc[ni] = __builtin_amdgcn_mfma_f32_16x16x32_bf16(ap, bv, oacc[ni], 0, 0, 0);
      }
    }
  }

#pragma unroll
  for (int ni = 0; ni < 4; ++ni)
#pragma unroll
    for (int r = 0; r < 4; ++r) {
      const size_t row = qrow0 + (wave << 4) + g4 + r;
      ctx[row * DIMD + h * DK + (ni << 4) + fr] = f2b(oacc[ni][r] / lrow[r]);
    }
}

__global__ __launch_bounds__(256) void copy_f32(
    const float* __restrict__ in, float* __restrict__ out, int n)
{
  const int stride = gridDim.x * blockDim.x * 4;
  for (int i = (blockIdx.x * blockDim.x + threadIdx.x) * 4; i < n; i += stride)
    *(float4*)(out + i) = *(const float4*)(in + i);
}

extern "C" void kernel_launch(void* const* d_in, const int* in_sizes, int n_in,
                              void* d_out, int out_size, void* d_ws, size_t ws_size,
                              hipStream_t stream) {
  const float* x     = (const float*)d_in[0];
  const float* w_qkv = (const float*)d_in[1];
  const float* b_qkv = (const float*)d_in[2];
  const float* w_out = (const float*)d_in[3];
  const float* b_out = (const float*)d_in[4];

  const size_t need = (size_t)MROWS * NQKV * sizeof(ushort_t);   // 48 MiB
  if (ws_size < need) return;

  ushort_t* qkv     = (ushort_t*)d_ws;   // [8192,3072] bf16 in ws
  ushort_t* ctx     = (ushort_t*)d_out;  // [8192,1024] bf16 scratch in d_out low bytes
  float*    out_tmp = (float*)d_ws;      // [8192,1024] f32, overwrites dead qkv region
  float*    out     = (float*)d_out;     // final f32 output

  // 1) QKV projection (f32 inputs cast in staging) -> bf16 qkv
  gemm_bt_bias<true, false><<<dim3((MROWS / 128) * (NQKV / 128)), dim3(256), 0, stream>>>(
      (const void*)x, w_qkv, b_qkv, (void*)qkv, MROWS, NQKV, DIMD);
  // 2) causal flash attention -> bf16 ctx (scratch inside d_out)
  attn_fused<<<dim3(BB * NH * (TT / 64)), dim3(256), 0, stream>>>(qkv, ctx);
  // 3) output projection: reads bf16 ctx, writes f32 into ws
  gemm_bt_bias<false, true><<<dim3((MROWS / 128) * (DIMD / 128)), dim3(256), 0, stream>>>(
      (const void*)ctx, w_out, b_out, (void*)out_tmp, MROWS, DIMD, DIMD);
  // 4) final f32 result -> d_out (fully overwrites the ctx scratch)
  copy_f32<<<dim3(2048), dim3(256), 0, stream>>>(out_tmp, out, MROWS * DIMD);
}